// Round 1
// baseline (1148.726 us; speedup 1.0000x reference)
//
#include <hip/hip_runtime.h>

#define NN 100000
#define NE 3200000
#define DIN 128
#define DHID 16
#define DOUT 2

// ---------------- degree ----------------
__global__ __launch_bounds__(256) void k_init_deg(float* __restrict__ deg) {
    int v = blockIdx.x * 256 + threadIdx.x;
    if (v < NN) deg[v] = 1.0f;  // self loop
}

__global__ __launch_bounds__(256) void k_count_deg(const int* __restrict__ dst,
                                                   float* __restrict__ deg) {
    int e = blockIdx.x * 256 + threadIdx.x;
    if (e < NE) atomicAdd(&deg[dst[e]], 1.0f);
}

__global__ __launch_bounds__(256) void k_dinv(const float* __restrict__ deg,
                                              float* __restrict__ dinv) {
    int v = blockIdx.x * 256 + threadIdx.x;
    if (v < NN) dinv[v] = rsqrtf(deg[v]);
}

// ---------------- layer 1: h1 = x @ W1; g1 = h1*dinv; out1 = g1*dinv (self loop) ----
__global__ __launch_bounds__(256) void k_mm1(const float* __restrict__ x,
                                             const float* __restrict__ W1,
                                             const float* __restrict__ dinv,
                                             float* __restrict__ g1,
                                             float* __restrict__ out1) {
    __shared__ float Ws[DIN * DHID];  // 8 KB
    for (int i = threadIdx.x; i < DIN * DHID; i += 256) Ws[i] = W1[i];
    __syncthreads();
    int v = blockIdx.x * 256 + threadIdx.x;
    if (v >= NN) return;
    float acc[DHID];
#pragma unroll
    for (int j = 0; j < DHID; ++j) acc[j] = 0.0f;
    const float4* xr = (const float4*)(x + (size_t)v * DIN);
#pragma unroll
    for (int k4 = 0; k4 < DIN / 4; ++k4) {
        float4 xv = xr[k4];
        const float* w0 = &Ws[(k4 * 4 + 0) * DHID];
        const float* w1 = &Ws[(k4 * 4 + 1) * DHID];
        const float* w2 = &Ws[(k4 * 4 + 2) * DHID];
        const float* w3 = &Ws[(k4 * 4 + 3) * DHID];
#pragma unroll
        for (int j = 0; j < DHID; ++j)
            acc[j] += xv.x * w0[j] + xv.y * w1[j] + xv.z * w2[j] + xv.w * w3[j];
    }
    float dv = dinv[v];
    float* gp = g1 + (size_t)v * DHID;
    float* op = out1 + (size_t)v * DHID;
#pragma unroll
    for (int j = 0; j < DHID; ++j) {
        float g = acc[j] * dv;
        gp[j] = g;
        op[j] = g * dv;  // self-loop contribution: h[v]*dinv[v]^2
    }
}

// ---------------- layer 1 edge scatter: out1[dst] += g1[src]*dinv[dst] ---------
__global__ __launch_bounds__(256) void k_scatter1(const int* __restrict__ src,
                                                  const int* __restrict__ dst,
                                                  const float* __restrict__ dinv,
                                                  const float* __restrict__ g1,
                                                  float* __restrict__ out1) {
    long long t = (long long)blockIdx.x * 256 + threadIdx.x;
    int e = (int)(t >> 2);
    int q = (int)(t & 3);
    if (e >= NE) return;
    int u = src[e];
    int v = dst[e];
    float s = dinv[v];
    float4 g = ((const float4*)(g1 + (size_t)u * DHID))[q];
    float* o = out1 + (size_t)v * DHID + q * 4;
    atomicAdd(o + 0, g.x * s);
    atomicAdd(o + 1, g.y * s);
    atomicAdd(o + 2, g.z * s);
    atomicAdd(o + 3, g.w * s);
}

// ---------------- layer 2: t = relu(out1+b1); h2 = t@W2; g2=h2*dinv; out2=g2*dinv --
__global__ __launch_bounds__(256) void k_mm2(const float* __restrict__ out1,
                                             const float* __restrict__ b1,
                                             const float* __restrict__ W2,
                                             const float* __restrict__ dinv,
                                             float* __restrict__ g2,
                                             float* __restrict__ out2) {
    int v = blockIdx.x * 256 + threadIdx.x;
    if (v >= NN) return;
    const float4* r = (const float4*)(out1 + (size_t)v * DHID);
    float h0 = 0.0f, h1 = 0.0f;
#pragma unroll
    for (int q = 0; q < 4; ++q) {
        float4 a = r[q];
        float tt[4] = {a.x, a.y, a.z, a.w};
#pragma unroll
        for (int i = 0; i < 4; ++i) {
            int j = q * 4 + i;
            float tv = fmaxf(tt[i] + b1[j], 0.0f);
            h0 += tv * W2[j * DOUT + 0];
            h1 += tv * W2[j * DOUT + 1];
        }
    }
    float dv = dinv[v];
    g2[v * 2 + 0] = h0 * dv;
    g2[v * 2 + 1] = h1 * dv;
    out2[v * 2 + 0] = h0 * dv * dv;  // self loop
    out2[v * 2 + 1] = h1 * dv * dv;
}

// ---------------- layer 2 edge scatter ----------------
__global__ __launch_bounds__(256) void k_scatter2(const int* __restrict__ src,
                                                  const int* __restrict__ dst,
                                                  const float* __restrict__ dinv,
                                                  const float* __restrict__ g2,
                                                  float* __restrict__ out2) {
    int e = blockIdx.x * 256 + threadIdx.x;
    if (e >= NE) return;
    int u = src[e];
    int v = dst[e];
    float s = dinv[v];
    float2 g = *(const float2*)(g2 + (size_t)u * 2);
    atomicAdd(&out2[v * 2 + 0], g.x * s);
    atomicAdd(&out2[v * 2 + 1], g.y * s);
}

// ---------------- epilogue: + b2, log_softmax ----------------
__global__ __launch_bounds__(256) void k_logsm(const float* __restrict__ out2,
                                               const float* __restrict__ b2,
                                               float* __restrict__ out) {
    int v = blockIdx.x * 256 + threadIdx.x;
    if (v >= NN) return;
    float a = out2[v * 2 + 0] + b2[0];
    float b = out2[v * 2 + 1] + b2[1];
    float m = fmaxf(a, b);
    float lse = m + logf(expf(a - m) + expf(b - m));
    out[v * 2 + 0] = a - lse;
    out[v * 2 + 1] = b - lse;
}

extern "C" void kernel_launch(void* const* d_in, const int* in_sizes, int n_in,
                              void* d_out, int out_size, void* d_ws, size_t ws_size,
                              hipStream_t stream) {
    const float* x  = (const float*)d_in[0];
    const float* W1 = (const float*)d_in[1];
    const float* b1 = (const float*)d_in[2];
    const float* W2 = (const float*)d_in[3];
    const float* b2 = (const float*)d_in[4];
    const int* ei   = (const int*)d_in[5];
    const int* src = ei;
    const int* dst = ei + NE;

    float* ws   = (float*)d_ws;
    float* deg  = ws;                 // NN
    float* dinv = ws + NN;            // NN
    float* g1   = ws + 2 * NN;        // 16*NN
    float* out1 = ws + 18 * NN;       // 16*NN
    float* g2   = ws + 34 * NN;       // 2*NN
    float* out2 = ws + 36 * NN;       // 2*NN

    float* out = (float*)d_out;

    const int NB_N = (NN + 255) / 256;       // node-parallel
    const int NB_E = (NE + 255) / 256;       // edge-parallel
    const int NB_E4 = (NE * 4 + 255) / 256;  // 4 threads/edge

    k_init_deg<<<NB_N, 256, 0, stream>>>(deg);
    k_count_deg<<<NB_E, 256, 0, stream>>>(dst, deg);
    k_dinv<<<NB_N, 256, 0, stream>>>(deg, dinv);
    k_mm1<<<NB_N, 256, 0, stream>>>(x, W1, dinv, g1, out1);
    k_scatter1<<<NB_E4, 256, 0, stream>>>(src, dst, dinv, g1, out1);
    k_mm2<<<NB_N, 256, 0, stream>>>(out1, b1, W2, dinv, g2, out2);
    k_scatter2<<<NB_E, 256, 0, stream>>>(src, dst, dinv, g2, out2);
    k_logsm<<<NB_N, 256, 0, stream>>>(out2, b2, out);
}

// Round 2
// 839.673 us; speedup vs baseline: 1.3681x; 1.3681x over previous
//
#include <hip/hip_runtime.h>

#define NN 100000
#define NE 3200000
#define DIN 128
#define DHID 16
#define DOUT 2
#define SCAN_T 1024
#define SCAN_CH ((NN + SCAN_T - 1) / SCAN_T)  // 98

// ---------------- CSR build ----------------
__global__ __launch_bounds__(256) void k_zero_counts(int* __restrict__ counts) {
    int v = blockIdx.x * 256 + threadIdx.x;
    if (v < NN) counts[v] = 0;
}

__global__ __launch_bounds__(256) void k_hist(const int* __restrict__ dst,
                                              int* __restrict__ counts) {
    int e = blockIdx.x * 256 + threadIdx.x;
    if (e < NE) atomicAdd(&counts[dst[e]], 1);
}

// exclusive scan over counts -> rowstart & cursor; also dinv = rsqrt(deg+1)
__global__ __launch_bounds__(SCAN_T) void k_scan(const int* __restrict__ counts,
                                                 int* __restrict__ rowstart,
                                                 int* __restrict__ cursor,
                                                 float* __restrict__ dinv) {
    __shared__ int part[SCAN_T];
    int t = threadIdx.x;
    int beg = t * SCAN_CH;
    int end = min(beg + SCAN_CH, NN);
    int s = 0;
    for (int i = beg; i < end; ++i) s += counts[i];
    part[t] = s;
    __syncthreads();
    for (int off = 1; off < SCAN_T; off <<= 1) {
        int v = part[t];
        int add = (t >= off) ? part[t - off] : 0;
        __syncthreads();
        part[t] = v + add;
        __syncthreads();
    }
    int pre = (t == 0) ? 0 : part[t - 1];
    for (int i = beg; i < end; ++i) {
        int c = counts[i];
        rowstart[i] = pre;
        cursor[i] = pre;
        dinv[i] = rsqrtf((float)(c + 1));
        pre += c;
    }
    if (t == SCAN_T - 1) rowstart[NN] = NE;
}

__global__ __launch_bounds__(256) void k_fill(const int* __restrict__ src,
                                              const int* __restrict__ dst,
                                              int* __restrict__ cursor,
                                              int* __restrict__ esrc) {
    int e = blockIdx.x * 256 + threadIdx.x;
    if (e >= NE) return;
    int pos = atomicAdd(&cursor[dst[e]], 1);
    esrc[pos] = src[e];
}

// ---------------- layer 1 transform: g1 = (x @ W1) * dinv ----------------
__global__ __launch_bounds__(256) void k_mm1(const float* __restrict__ x,
                                             const float* __restrict__ W1,
                                             const float* __restrict__ dinv,
                                             float* __restrict__ g1) {
    __shared__ float Ws[DIN * DHID];  // 8 KB
    for (int i = threadIdx.x; i < DIN * DHID; i += 256) Ws[i] = W1[i];
    __syncthreads();
    int v = blockIdx.x * 256 + threadIdx.x;
    if (v >= NN) return;
    float acc[DHID];
#pragma unroll
    for (int j = 0; j < DHID; ++j) acc[j] = 0.0f;
    const float4* xr = (const float4*)(x + (size_t)v * DIN);
#pragma unroll
    for (int k4 = 0; k4 < DIN / 4; ++k4) {
        float4 xv = xr[k4];
        const float* w0 = &Ws[(k4 * 4 + 0) * DHID];
        const float* w1 = &Ws[(k4 * 4 + 1) * DHID];
        const float* w2 = &Ws[(k4 * 4 + 2) * DHID];
        const float* w3 = &Ws[(k4 * 4 + 3) * DHID];
#pragma unroll
        for (int j = 0; j < DHID; ++j)
            acc[j] += xv.x * w0[j] + xv.y * w1[j] + xv.z * w2[j] + xv.w * w3[j];
    }
    float dv = dinv[v];
    float* gp = g1 + (size_t)v * DHID;
#pragma unroll
    for (int j = 0; j < DHID; ++j) gp[j] = acc[j] * dv;
}

// ---------------- layer 1 gather: out1[v] = (sum_{u in N(v)} g1[u] + g1[v]) * dinv[v]
// 16 lanes per node, one lane per hidden channel
__global__ __launch_bounds__(256) void k_gather1(const int* __restrict__ rowstart,
                                                 const int* __restrict__ esrc,
                                                 const float* __restrict__ dinv,
                                                 const float* __restrict__ g1,
                                                 float* __restrict__ out1) {
    int t = blockIdx.x * 256 + threadIdx.x;
    int v = t >> 4;
    int j = t & 15;
    if (v >= NN) return;
    int beg = rowstart[v];
    int end = rowstart[v + 1];
    float acc = g1[(size_t)v * DHID + j];  // self loop
    for (int p = beg; p < end; ++p) {
        int u = esrc[p];
        acc += g1[(size_t)u * DHID + j];
    }
    out1[(size_t)v * DHID + j] = acc * dinv[v];
}

// ---------------- layer 2 transform: t = relu(out1 + b1); g2 = (t @ W2) * dinv ----
__global__ __launch_bounds__(256) void k_mm2(const float* __restrict__ out1,
                                             const float* __restrict__ b1,
                                             const float* __restrict__ W2,
                                             const float* __restrict__ dinv,
                                             float* __restrict__ g2) {
    int v = blockIdx.x * 256 + threadIdx.x;
    if (v >= NN) return;
    const float4* r = (const float4*)(out1 + (size_t)v * DHID);
    float h0 = 0.0f, h1 = 0.0f;
#pragma unroll
    for (int q = 0; q < 4; ++q) {
        float4 a = r[q];
        float tt[4] = {a.x, a.y, a.z, a.w};
#pragma unroll
        for (int i = 0; i < 4; ++i) {
            int j = q * 4 + i;
            float tv = fmaxf(tt[i] + b1[j], 0.0f);
            h0 += tv * W2[j * DOUT + 0];
            h1 += tv * W2[j * DOUT + 1];
        }
    }
    float dv = dinv[v];
    g2[v * 2 + 0] = h0 * dv;
    g2[v * 2 + 1] = h1 * dv;
}

// ---------------- layer 2 gather + bias + log_softmax (2 lanes/node) ----------
__global__ __launch_bounds__(256) void k_gather2(const int* __restrict__ rowstart,
                                                 const int* __restrict__ esrc,
                                                 const float* __restrict__ dinv,
                                                 const float* __restrict__ g2,
                                                 const float* __restrict__ b2,
                                                 float* __restrict__ out) {
    int t = blockIdx.x * 256 + threadIdx.x;
    int v = t >> 1;
    int j = t & 1;
    if (v >= NN) return;
    int beg = rowstart[v];
    int end = rowstart[v + 1];
    float acc = g2[v * 2 + j];  // self loop
    for (int p = beg; p < end; ++p) {
        int u = esrc[p];
        acc += g2[u * 2 + j];
    }
    float o = acc * dinv[v] + b2[j];
    float other = __shfl_xor(o, 1);
    float m = fmaxf(o, other);
    float lse = m + logf(expf(o - m) + expf(other - m));
    out[v * 2 + j] = o - lse;
}

extern "C" void kernel_launch(void* const* d_in, const int* in_sizes, int n_in,
                              void* d_out, int out_size, void* d_ws, size_t ws_size,
                              hipStream_t stream) {
    const float* x  = (const float*)d_in[0];
    const float* W1 = (const float*)d_in[1];
    const float* b1 = (const float*)d_in[2];
    const float* W2 = (const float*)d_in[3];
    const float* b2 = (const float*)d_in[4];
    const int* ei   = (const int*)d_in[5];
    const int* src = ei;
    const int* dst = ei + NE;

    // workspace layout (all 4B elems; rowstart padded to NN+8 to keep
    // downstream float4 regions 16B-aligned)
    int* counts   = (int*)d_ws;            // NN
    int* rowstart = counts + NN;           // NN+8 (uses NN+1)
    int* cursor   = rowstart + NN + 8;     // NN
    int* esrc     = cursor + NN;           // NE
    float* dinv   = (float*)(esrc + NE);   // NN
    float* g1     = dinv + NN;             // 16*NN
    float* out1   = g1 + 16 * NN;          // 16*NN  (16B-aligned)
    float* g2     = out1 + 16 * NN;        // 2*NN

    float* out = (float*)d_out;

    const int NB_N = (NN + 255) / 256;
    const int NB_E = (NE + 255) / 256;

    k_zero_counts<<<NB_N, 256, 0, stream>>>(counts);
    k_hist<<<NB_E, 256, 0, stream>>>(dst, counts);
    k_scan<<<1, SCAN_T, 0, stream>>>(counts, rowstart, cursor, dinv);
    k_fill<<<NB_E, 256, 0, stream>>>(src, dst, cursor, esrc);
    k_mm1<<<NB_N, 256, 0, stream>>>(x, W1, dinv, g1);
    k_gather1<<<(NN * 16 + 255) / 256, 256, 0, stream>>>(rowstart, esrc, dinv, g1, out1);
    k_mm2<<<NB_N, 256, 0, stream>>>(out1, b1, W2, dinv, g2);
    k_gather2<<<(NN * 2 + 255) / 256, 256, 0, stream>>>(rowstart, esrc, dinv, g2, b2, out);
}

// Round 3
// 217.129 us; speedup vs baseline: 5.2905x; 3.8672x over previous
//
#include <hip/hip_runtime.h>

#define NN 100000
#define NE 3200000
#define DIN 128
#define DHID 16
#define DOUT 2
#define NBUCK 391            // ceil(NN/256) buckets of 256 dst nodes
#define EPT 16               // edges per thread in hist/fill
#define BHT 1024             // threads in hist/fill blocks
#define EPB (BHT * EPT)      // 16384 edges per block
#define NBB ((NE + EPB - 1) / EPB)  // 196

// ---------------- bucket count zero ----------------
__global__ __launch_bounds__(512) void k_zero_b(int* __restrict__ bcount) {
    int t = threadIdx.x;
    if (t < NBUCK) bcount[t] = 0;
}

// ---------------- coarse bucket histogram (dst >> 8) ----------------
__global__ __launch_bounds__(BHT) void k_bhist(const int* __restrict__ dst,
                                               int* __restrict__ bcount) {
    __shared__ int h[NBUCK];
    int t = threadIdx.x;
    for (int i = t; i < NBUCK; i += BHT) h[i] = 0;
    __syncthreads();
    long long base = (long long)blockIdx.x * EPB;
#pragma unroll
    for (int k = 0; k < EPT; ++k) {
        long long e = base + (long long)k * BHT + t;
        if (e < NE) atomicAdd(&h[((unsigned)dst[e]) >> 8], 1);
    }
    __syncthreads();
    for (int i = t; i < NBUCK; i += BHT) {
        int c = h[i];
        if (c) atomicAdd(&bcount[i], c);
    }
}

// ---------------- scan 391 bucket counts ----------------
__global__ __launch_bounds__(512) void k_bscan(const int* __restrict__ bcount,
                                               int* __restrict__ bstart,
                                               int* __restrict__ bcursor) {
    __shared__ int sc[512];
    int t = threadIdx.x;
    int c = (t < NBUCK) ? bcount[t] : 0;
    sc[t] = c;
    __syncthreads();
    for (int off = 1; off < 512; off <<= 1) {
        int v = sc[t];
        int add = (t >= off) ? sc[t - off] : 0;
        __syncthreads();
        sc[t] = v + add;
        __syncthreads();
    }
    int excl = sc[t] - c;
    if (t <= NBUCK) bstart[t] = excl;  // bstart[NBUCK] == NE
    if (t < NBUCK) bcursor[t] = excl;
}

// ---------------- bucket the edges: packed = (dstLow<<24)|src ----------------
__global__ __launch_bounds__(BHT) void k_bfill(const int* __restrict__ src,
                                               const int* __restrict__ dst,
                                               int* __restrict__ bcursor,
                                               unsigned* __restrict__ packed) {
    __shared__ int h[NBUCK];     // local hist, then local cursor
    __shared__ int hbase[NBUCK]; // reserved global base per bucket
    int t = threadIdx.x;
    for (int i = t; i < NBUCK; i += BHT) h[i] = 0;
    __syncthreads();
    long long base = (long long)blockIdx.x * EPB;
    int ed[EPT], es[EPT];
#pragma unroll
    for (int k = 0; k < EPT; ++k) {
        long long e = base + (long long)k * BHT + t;
        if (e < NE) {
            ed[k] = dst[e];
            es[k] = src[e];
            atomicAdd(&h[((unsigned)ed[k]) >> 8], 1);
        } else {
            ed[k] = -1;
            es[k] = 0;
        }
    }
    __syncthreads();
    // reserve contiguous runs, reset local cursors
    for (int i = t; i < NBUCK; i += BHT) {
        int c = h[i];
        hbase[i] = c ? atomicAdd(&bcursor[i], c) : 0;
    }
    __syncthreads();
    for (int i = t; i < NBUCK; i += BHT) h[i] = 0;
    __syncthreads();
#pragma unroll
    for (int k = 0; k < EPT; ++k) {
        if (ed[k] >= 0) {
            unsigned d = (unsigned)ed[k];
            int b = d >> 8;
            int off = atomicAdd(&h[b], 1);
            packed[hbase[b] + off] = ((d & 255u) << 24) | (unsigned)es[k];
        }
    }
}

// ---------------- per-bucket exact sort -> rowstart, dinv, esrc ----------------
__global__ __launch_bounds__(256) void k_pass2(const int* __restrict__ bstart,
                                               const unsigned* __restrict__ packed,
                                               int* __restrict__ rowstart,
                                               float* __restrict__ dinv,
                                               int* __restrict__ esrc) {
    __shared__ int h[256], sc[256], cur[256];
    int b = blockIdx.x;
    int t = threadIdx.x;
    int dst0 = b << 8;
    int ebeg = bstart[b];
    int eend = bstart[b + 1];
    h[t] = 0;
    __syncthreads();
    for (int p = ebeg + t; p < eend; p += 256)
        atomicAdd(&h[packed[p] >> 24], 1);
    __syncthreads();
    int c = h[t];
    sc[t] = c;
    __syncthreads();
    for (int off = 1; off < 256; off <<= 1) {
        int v = sc[t];
        int add = (t >= off) ? sc[t - off] : 0;
        __syncthreads();
        sc[t] = v + add;
        __syncthreads();
    }
    int gpos = ebeg + sc[t] - c;  // global start of this dst's segment
    int v = dst0 + t;
    if (v < NN) {
        rowstart[v] = gpos;
        dinv[v] = rsqrtf((float)(c + 1));
    }
    cur[t] = gpos;
    if (b == 0 && t == 0) rowstart[NN] = NE;
    __syncthreads();
    for (int p = ebeg + t; p < eend; p += 256) {
        unsigned pk = packed[p];
        int pos = atomicAdd(&cur[pk >> 24], 1);
        esrc[pos] = (int)(pk & 0xFFFFFFu);
    }
}

// ---------------- layer 1 transform: g1 = (x @ W1) * dinv ----------------
__global__ __launch_bounds__(256) void k_mm1(const float* __restrict__ x,
                                             const float* __restrict__ W1,
                                             const float* __restrict__ dinv,
                                             float* __restrict__ g1) {
    __shared__ float Ws[DIN * DHID];  // 8 KB
    for (int i = threadIdx.x; i < DIN * DHID; i += 256) Ws[i] = W1[i];
    __syncthreads();
    int v = blockIdx.x * 256 + threadIdx.x;
    if (v >= NN) return;
    float acc[DHID];
#pragma unroll
    for (int j = 0; j < DHID; ++j) acc[j] = 0.0f;
    const float4* xr = (const float4*)(x + (size_t)v * DIN);
#pragma unroll
    for (int k4 = 0; k4 < DIN / 4; ++k4) {
        float4 xv = xr[k4];
        const float* w0 = &Ws[(k4 * 4 + 0) * DHID];
        const float* w1 = &Ws[(k4 * 4 + 1) * DHID];
        const float* w2 = &Ws[(k4 * 4 + 2) * DHID];
        const float* w3 = &Ws[(k4 * 4 + 3) * DHID];
#pragma unroll
        for (int j = 0; j < DHID; ++j)
            acc[j] += xv.x * w0[j] + xv.y * w1[j] + xv.z * w2[j] + xv.w * w3[j];
    }
    float dv = dinv[v];
    float* gp = g1 + (size_t)v * DHID;
#pragma unroll
    for (int j = 0; j < DHID; ++j) gp[j] = acc[j] * dv;
}

// ---------------- layer 1 gather (16 lanes/node) ----------------
__global__ __launch_bounds__(256) void k_gather1(const int* __restrict__ rowstart,
                                                 const int* __restrict__ esrc,
                                                 const float* __restrict__ dinv,
                                                 const float* __restrict__ g1,
                                                 float* __restrict__ out1) {
    int t = blockIdx.x * 256 + threadIdx.x;
    int v = t >> 4;
    int j = t & 15;
    if (v >= NN) return;
    int beg = rowstart[v];
    int end = rowstart[v + 1];
    float acc = g1[(size_t)v * DHID + j];  // self loop
    for (int p = beg; p < end; ++p) {
        int u = esrc[p];
        acc += g1[(size_t)u * DHID + j];
    }
    out1[(size_t)v * DHID + j] = acc * dinv[v];
}

// ---------------- layer 2 transform ----------------
__global__ __launch_bounds__(256) void k_mm2(const float* __restrict__ out1,
                                             const float* __restrict__ b1,
                                             const float* __restrict__ W2,
                                             const float* __restrict__ dinv,
                                             float* __restrict__ g2) {
    int v = blockIdx.x * 256 + threadIdx.x;
    if (v >= NN) return;
    const float4* r = (const float4*)(out1 + (size_t)v * DHID);
    float h0 = 0.0f, h1 = 0.0f;
#pragma unroll
    for (int q = 0; q < 4; ++q) {
        float4 a = r[q];
        float tt[4] = {a.x, a.y, a.z, a.w};
#pragma unroll
        for (int i = 0; i < 4; ++i) {
            int j = q * 4 + i;
            float tv = fmaxf(tt[i] + b1[j], 0.0f);
            h0 += tv * W2[j * DOUT + 0];
            h1 += tv * W2[j * DOUT + 1];
        }
    }
    float dv = dinv[v];
    g2[v * 2 + 0] = h0 * dv;
    g2[v * 2 + 1] = h1 * dv;
}

// ---------------- layer 2 gather + bias + log_softmax (2 lanes/node) ------
__global__ __launch_bounds__(256) void k_gather2(const int* __restrict__ rowstart,
                                                 const int* __restrict__ esrc,
                                                 const float* __restrict__ dinv,
                                                 const float* __restrict__ g2,
                                                 const float* __restrict__ b2,
                                                 float* __restrict__ out) {
    int t = blockIdx.x * 256 + threadIdx.x;
    int v = t >> 1;
    int j = t & 1;
    if (v >= NN) return;
    int beg = rowstart[v];
    int end = rowstart[v + 1];
    float acc = g2[v * 2 + j];  // self loop
    for (int p = beg; p < end; ++p) {
        int u = esrc[p];
        acc += g2[u * 2 + j];
    }
    float o = acc * dinv[v] + b2[j];
    float other = __shfl_xor(o, 1);
    float m = fmaxf(o, other);
    float lse = m + logf(expf(o - m) + expf(other - m));
    out[v * 2 + j] = o - lse;
}

extern "C" void kernel_launch(void* const* d_in, const int* in_sizes, int n_in,
                              void* d_out, int out_size, void* d_ws, size_t ws_size,
                              hipStream_t stream) {
    const float* x  = (const float*)d_in[0];
    const float* W1 = (const float*)d_in[1];
    const float* b1 = (const float*)d_in[2];
    const float* W2 = (const float*)d_in[3];
    const float* b2 = (const float*)d_in[4];
    const int* ei   = (const int*)d_in[5];
    const int* src = ei;
    const int* dst = ei + NE;

    // workspace (ints). packed (NE) is dead after k_pass2; g1 (16NN) and
    // out1 (16NN) alias it (16NN + 16NN == 3.2M == NE). Stream order makes
    // the aliasing safe.
    int* ws       = (int*)d_ws;
    int* bcount   = ws;                    // 400
    int* bstart   = ws + 400;              // 400 (uses NBUCK+1)
    int* bcursor  = ws + 800;              // 400
    int* rowstart = ws + 1200;             // NN+16
    float* dinv   = (float*)(ws + 1200 + NN + 16);    // NN
    int* esrc     = ws + 1200 + 2 * NN + 16;          // NE
    unsigned* packed = (unsigned*)(esrc + NE);        // NE
    float* g1     = (float*)packed;        // 16*NN  (aliases packed)
    float* out1   = g1 + 16 * NN;          // 16*NN  (aliases packed)
    float* g2     = (float*)(packed + NE); // 2*NN

    float* out = (float*)d_out;

    const int NB_N = (NN + 255) / 256;  // 391

    k_zero_b<<<1, 512, 0, stream>>>(bcount);
    k_bhist<<<NBB, BHT, 0, stream>>>(dst, bcount);
    k_bscan<<<1, 512, 0, stream>>>(bcount, bstart, bcursor);
    k_bfill<<<NBB, BHT, 0, stream>>>(src, dst, bcursor, packed);
    k_pass2<<<NBUCK, 256, 0, stream>>>(bstart, packed, rowstart, dinv, esrc);
    k_mm1<<<NB_N, 256, 0, stream>>>(x, W1, dinv, g1);
    k_gather1<<<(NN * 16 + 255) / 256, 256, 0, stream>>>(rowstart, esrc, dinv, g1, out1);
    k_mm2<<<NB_N, 256, 0, stream>>>(out1, b1, W2, dinv, g2);
    k_gather2<<<(NN * 2 + 255) / 256, 256, 0, stream>>>(rowstart, esrc, dinv, g2, b2, out);
}

// Round 4
// 161.710 us; speedup vs baseline: 7.1036x; 1.3427x over previous
//
#include <hip/hip_runtime.h>

#define NN 100000
#define NE 3200000
#define DIN 128
#define DHID 16
#define DOUT 2
#define NBUCK 391            // ceil(NN/256) buckets of 256 dst nodes
#define EPT 16               // edges per thread in hist/fill
#define BHT 1024             // threads in hist/fill blocks
#define EPB (BHT * EPT)      // 16384 edges per block
#define NBB ((NE + EPB - 1) / EPB)  // 196

// round-to-nearest-even f32 -> bf16 (bits)
__device__ __forceinline__ unsigned f2bf(float f) {
    unsigned u = __float_as_uint(f);
    return (u + 0x7FFFu + ((u >> 16) & 1u)) >> 16;
}
__device__ __forceinline__ float bflo(unsigned a) { return __uint_as_float(a << 16); }
__device__ __forceinline__ float bfhi(unsigned a) { return __uint_as_float(a & 0xFFFF0000u); }

// ---------------- bucket count zero ----------------
__global__ __launch_bounds__(512) void k_zero_b(int* __restrict__ bcount) {
    int t = threadIdx.x;
    if (t < NBUCK) bcount[t] = 0;
}

// ---------------- coarse bucket histogram (dst >> 8) ----------------
__global__ __launch_bounds__(BHT) void k_bhist(const int* __restrict__ dst,
                                               int* __restrict__ bcount) {
    __shared__ int h[NBUCK];
    int t = threadIdx.x;
    for (int i = t; i < NBUCK; i += BHT) h[i] = 0;
    __syncthreads();
    long long base = (long long)blockIdx.x * EPB;
#pragma unroll
    for (int k = 0; k < EPT; ++k) {
        long long e = base + (long long)k * BHT + t;
        if (e < NE) atomicAdd(&h[((unsigned)dst[e]) >> 8], 1);
    }
    __syncthreads();
    for (int i = t; i < NBUCK; i += BHT) {
        int c = h[i];
        if (c) atomicAdd(&bcount[i], c);
    }
}

// ---------------- scan 391 bucket counts ----------------
__global__ __launch_bounds__(512) void k_bscan(const int* __restrict__ bcount,
                                               int* __restrict__ bstart,
                                               int* __restrict__ bcursor) {
    __shared__ int sc[512];
    int t = threadIdx.x;
    int c = (t < NBUCK) ? bcount[t] : 0;
    sc[t] = c;
    __syncthreads();
    for (int off = 1; off < 512; off <<= 1) {
        int v = sc[t];
        int add = (t >= off) ? sc[t - off] : 0;
        __syncthreads();
        sc[t] = v + add;
        __syncthreads();
    }
    int excl = sc[t] - c;
    if (t <= NBUCK) bstart[t] = excl;  // bstart[NBUCK] == NE
    if (t < NBUCK) bcursor[t] = excl;
}

// ---------------- bucket the edges: packed = (dstLow<<24)|src ----------------
__global__ __launch_bounds__(BHT) void k_bfill(const int* __restrict__ src,
                                               const int* __restrict__ dst,
                                               int* __restrict__ bcursor,
                                               unsigned* __restrict__ packed) {
    __shared__ int h[NBUCK];     // local hist, then local cursor
    __shared__ int hbase[NBUCK]; // reserved global base per bucket
    int t = threadIdx.x;
    for (int i = t; i < NBUCK; i += BHT) h[i] = 0;
    __syncthreads();
    long long base = (long long)blockIdx.x * EPB;
    int ed[EPT], es[EPT];
#pragma unroll
    for (int k = 0; k < EPT; ++k) {
        long long e = base + (long long)k * BHT + t;
        if (e < NE) {
            ed[k] = dst[e];
            es[k] = src[e];
            atomicAdd(&h[((unsigned)ed[k]) >> 8], 1);
        } else {
            ed[k] = -1;
            es[k] = 0;
        }
    }
    __syncthreads();
    for (int i = t; i < NBUCK; i += BHT) {
        int c = h[i];
        hbase[i] = c ? atomicAdd(&bcursor[i], c) : 0;
    }
    __syncthreads();
    for (int i = t; i < NBUCK; i += BHT) h[i] = 0;
    __syncthreads();
#pragma unroll
    for (int k = 0; k < EPT; ++k) {
        if (ed[k] >= 0) {
            unsigned d = (unsigned)ed[k];
            int b = d >> 8;
            int off = atomicAdd(&h[b], 1);
            packed[hbase[b] + off] = ((d & 255u) << 24) | (unsigned)es[k];
        }
    }
}

// ---------------- per-bucket exact sort -> rowstart, dinv, esrc ----------------
__global__ __launch_bounds__(256) void k_pass2(const int* __restrict__ bstart,
                                               const unsigned* __restrict__ packed,
                                               int* __restrict__ rowstart,
                                               float* __restrict__ dinv,
                                               int* __restrict__ esrc) {
    __shared__ int h[256], sc[256], cur[256];
    int b = blockIdx.x;
    int t = threadIdx.x;
    int dst0 = b << 8;
    int ebeg = bstart[b];
    int eend = bstart[b + 1];
    h[t] = 0;
    __syncthreads();
    for (int p = ebeg + t; p < eend; p += 256)
        atomicAdd(&h[packed[p] >> 24], 1);
    __syncthreads();
    int c = h[t];
    sc[t] = c;
    __syncthreads();
    for (int off = 1; off < 256; off <<= 1) {
        int v = sc[t];
        int add = (t >= off) ? sc[t - off] : 0;
        __syncthreads();
        sc[t] = v + add;
        __syncthreads();
    }
    int gpos = ebeg + sc[t] - c;
    int v = dst0 + t;
    if (v < NN) {
        rowstart[v] = gpos;
        dinv[v] = rsqrtf((float)(c + 1));
    }
    cur[t] = gpos;
    if (b == 0 && t == 0) rowstart[NN] = NE;
    __syncthreads();
    for (int p = ebeg + t; p < eend; p += 256) {
        unsigned pk = packed[p];
        int pos = atomicAdd(&cur[pk >> 24], 1);
        esrc[pos] = (int)(pk & 0xFFFFFFu);
    }
}

// ---------------- layer 1 transform: g1b = bf16x2-packed (x @ W1) * dinv ----
__global__ __launch_bounds__(256) void k_mm1(const float* __restrict__ x,
                                             const float* __restrict__ W1,
                                             const float* __restrict__ dinv,
                                             unsigned* __restrict__ g1b) {
    __shared__ float Ws[DIN * DHID];  // 8 KB
    for (int i = threadIdx.x; i < DIN * DHID; i += 256) Ws[i] = W1[i];
    __syncthreads();
    int v = blockIdx.x * 256 + threadIdx.x;
    if (v >= NN) return;
    float acc[DHID];
#pragma unroll
    for (int j = 0; j < DHID; ++j) acc[j] = 0.0f;
    const float4* xr = (const float4*)(x + (size_t)v * DIN);
#pragma unroll
    for (int k4 = 0; k4 < DIN / 4; ++k4) {
        float4 xv = xr[k4];
        const float* w0 = &Ws[(k4 * 4 + 0) * DHID];
        const float* w1 = &Ws[(k4 * 4 + 1) * DHID];
        const float* w2 = &Ws[(k4 * 4 + 2) * DHID];
        const float* w3 = &Ws[(k4 * 4 + 3) * DHID];
#pragma unroll
        for (int j = 0; j < DHID; ++j)
            acc[j] += xv.x * w0[j] + xv.y * w1[j] + xv.z * w2[j] + xv.w * w3[j];
    }
    float dv = dinv[v];
    unsigned pk[8];
#pragma unroll
    for (int j = 0; j < 8; ++j)
        pk[j] = f2bf(acc[2 * j] * dv) | (f2bf(acc[2 * j + 1] * dv) << 16);
    uint4* gp = (uint4*)(g1b + (size_t)v * 8);
    gp[0] = make_uint4(pk[0], pk[1], pk[2], pk[3]);
    gp[1] = make_uint4(pk[4], pk[5], pk[6], pk[7]);
}

// ---------------- layer 1 gather: 8 lanes/node, 2 channels/lane, 4x unroll ----
__global__ __launch_bounds__(256) void k_gather1(const int* __restrict__ rowstart,
                                                 const int* __restrict__ esrc,
                                                 const float* __restrict__ dinv,
                                                 const unsigned* __restrict__ G,
                                                 float* __restrict__ out1) {
    int t = blockIdx.x * 256 + threadIdx.x;
    int v = t >> 3;
    int j = t & 7;
    if (v >= NN) return;
    int beg = rowstart[v];
    int end = rowstart[v + 1];
    unsigned a = G[(v << 3) + j];  // self loop
    float c0 = bflo(a), c1 = bfhi(a);
    int p = beg;
    int n4 = beg + ((end - beg) & ~3);
    for (; p < n4; p += 4) {
        int u0 = esrc[p], u1 = esrc[p + 1], u2 = esrc[p + 2], u3 = esrc[p + 3];
        unsigned b0 = G[(u0 << 3) + j];
        unsigned b1 = G[(u1 << 3) + j];
        unsigned b2 = G[(u2 << 3) + j];
        unsigned b3 = G[(u3 << 3) + j];
        c0 += bflo(b0) + bflo(b1) + bflo(b2) + bflo(b3);
        c1 += bfhi(b0) + bfhi(b1) + bfhi(b2) + bfhi(b3);
    }
    for (; p < end; ++p) {
        unsigned b = G[(esrc[p] << 3) + j];
        c0 += bflo(b);
        c1 += bfhi(b);
    }
    float dv = dinv[v];
    ((float2*)out1)[(v << 3) + j] = make_float2(c0 * dv, c1 * dv);
}

// ---------------- layer 2 transform ----------------
__global__ __launch_bounds__(256) void k_mm2(const float* __restrict__ out1,
                                             const float* __restrict__ b1,
                                             const float* __restrict__ W2,
                                             const float* __restrict__ dinv,
                                             float* __restrict__ g2) {
    int v = blockIdx.x * 256 + threadIdx.x;
    if (v >= NN) return;
    const float4* r = (const float4*)(out1 + (size_t)v * DHID);
    float h0 = 0.0f, h1 = 0.0f;
#pragma unroll
    for (int q = 0; q < 4; ++q) {
        float4 a = r[q];
        float tt[4] = {a.x, a.y, a.z, a.w};
#pragma unroll
        for (int i = 0; i < 4; ++i) {
            int j = q * 4 + i;
            float tv = fmaxf(tt[i] + b1[j], 0.0f);
            h0 += tv * W2[j * DOUT + 0];
            h1 += tv * W2[j * DOUT + 1];
        }
    }
    float dv = dinv[v];
    g2[v * 2 + 0] = h0 * dv;
    g2[v * 2 + 1] = h1 * dv;
}

// ---------------- layer 2 gather: 8 lanes/node = 4 edge-slots x 2 ch -------
__global__ __launch_bounds__(256) void k_gather2(const int* __restrict__ rowstart,
                                                 const int* __restrict__ esrc,
                                                 const float* __restrict__ dinv,
                                                 const float* __restrict__ g2,
                                                 const float* __restrict__ b2,
                                                 float* __restrict__ out) {
    int t = blockIdx.x * 256 + threadIdx.x;
    int v = t >> 3;
    if (v >= NN) return;
    int lane = t & 7;
    int ch = lane & 1;
    int slot = lane >> 1;
    int beg = rowstart[v];
    int end = rowstart[v + 1];
    float acc = 0.0f;
    for (int p = beg + slot; p < end; p += 4)
        acc += g2[(esrc[p] << 1) + ch];
    acc += __shfl_xor(acc, 2);
    acc += __shfl_xor(acc, 4);  // all slots summed; every lane has the total
    float o = (acc + g2[(v << 1) + ch]) * dinv[v] + b2[ch];
    float other = __shfl_xor(o, 1);
    float m = fmaxf(o, other);
    float lse = m + logf(expf(o - m) + expf(other - m));
    if (slot == 0) out[(v << 1) + ch] = o - lse;
}

extern "C" void kernel_launch(void* const* d_in, const int* in_sizes, int n_in,
                              void* d_out, int out_size, void* d_ws, size_t ws_size,
                              hipStream_t stream) {
    const float* x  = (const float*)d_in[0];
    const float* W1 = (const float*)d_in[1];
    const float* b1 = (const float*)d_in[2];
    const float* W2 = (const float*)d_in[3];
    const float* b2 = (const float*)d_in[4];
    const int* ei   = (const int*)d_in[5];
    const int* src = ei;
    const int* dst = ei + NE;

    // workspace (4B elems). packed (NE=12.8MB) is dead after k_pass2;
    // g1b (8NN uints = 3.2MB) and out1 (16NN floats = 6.4MB) alias it
    // (8NN + 16NN = 2.4M < NE = 3.2M). Stream order makes this safe.
    int* ws       = (int*)d_ws;
    int* bcount   = ws;                    // 400
    int* bstart   = ws + 400;              // 400 (uses NBUCK+1)
    int* bcursor  = ws + 800;              // 400
    int* rowstart = ws + 1200;             // NN+16
    float* dinv   = (float*)(ws + 1200 + NN + 16);    // NN
    int* esrc     = ws + 1200 + 2 * NN + 16;          // NE
    unsigned* packed = (unsigned*)(esrc + NE);        // NE
    unsigned* g1b = packed;                // 8*NN uints (aliases packed)
    float* out1   = (float*)(packed + 8 * NN);  // 16*NN floats (aliases packed)
    float* g2     = (float*)(packed + NE); // 2*NN

    float* out = (float*)d_out;

    const int NB_N = (NN + 255) / 256;  // 391

    k_zero_b<<<1, 512, 0, stream>>>(bcount);
    k_bhist<<<NBB, BHT, 0, stream>>>(dst, bcount);
    k_bscan<<<1, 512, 0, stream>>>(bcount, bstart, bcursor);
    k_bfill<<<NBB, BHT, 0, stream>>>(src, dst, bcursor, packed);
    k_pass2<<<NBUCK, 256, 0, stream>>>(bstart, packed, rowstart, dinv, esrc);
    k_mm1<<<NB_N, 256, 0, stream>>>(x, W1, dinv, g1b);
    k_gather1<<<(NN * 8 + 255) / 256, 256, 0, stream>>>(rowstart, esrc, dinv, g1b, out1);
    k_mm2<<<NB_N, 256, 0, stream>>>(out1, b1, W2, dinv, g2);
    k_gather2<<<(NN * 8 + 255) / 256, 256, 0, stream>>>(rowstart, esrc, dinv, g2, b2, out);
}

// Round 5
// 143.248 us; speedup vs baseline: 8.0192x; 1.1289x over previous
//
#include <hip/hip_runtime.h>

#define NN 100000
#define NE 3200000
#define DIN 128
#define DHID 16
#define DOUT 2
#define NBUCK 391            // ceil(NN/256) buckets of 256 dst nodes
#define EPT 16               // edges per thread in hist/fill
#define BHT 1024             // threads in hist/fill blocks
#define EPB (BHT * EPT)      // 16384 edges per block
#define NBB ((NE + EPB - 1) / EPB)  // 196

// round-to-nearest-even f32 -> bf16 (bits)
__device__ __forceinline__ unsigned f2bf(float f) {
    unsigned u = __float_as_uint(f);
    return (u + 0x7FFFu + ((u >> 16) & 1u)) >> 16;
}
__device__ __forceinline__ float bflo(unsigned a) { return __uint_as_float(a << 16); }
__device__ __forceinline__ float bfhi(unsigned a) { return __uint_as_float(a & 0xFFFF0000u); }

// ---------------- bucket count zero ----------------
__global__ __launch_bounds__(512) void k_zero_b(int* __restrict__ bcount) {
    int t = threadIdx.x;
    if (t < NBUCK) bcount[t] = 0;
}

// ---------------- coarse bucket histogram (dst >> 8) ----------------
__global__ __launch_bounds__(BHT) void k_bhist(const int* __restrict__ dst,
                                               int* __restrict__ bcount) {
    __shared__ int h[NBUCK];
    int t = threadIdx.x;
    for (int i = t; i < NBUCK; i += BHT) h[i] = 0;
    __syncthreads();
    long long base = (long long)blockIdx.x * EPB;
#pragma unroll
    for (int k = 0; k < EPT; ++k) {
        long long e = base + (long long)k * BHT + t;
        if (e < NE) atomicAdd(&h[((unsigned)dst[e]) >> 8], 1);
    }
    __syncthreads();
    for (int i = t; i < NBUCK; i += BHT) {
        int c = h[i];
        if (c) atomicAdd(&bcount[i], c);
    }
}

// ---------------- scan 391 bucket counts ----------------
__global__ __launch_bounds__(512) void k_bscan(const int* __restrict__ bcount,
                                               int* __restrict__ bstart,
                                               int* __restrict__ bcursor) {
    __shared__ int sc[512];
    int t = threadIdx.x;
    int c = (t < NBUCK) ? bcount[t] : 0;
    sc[t] = c;
    __syncthreads();
    for (int off = 1; off < 512; off <<= 1) {
        int v = sc[t];
        int add = (t >= off) ? sc[t - off] : 0;
        __syncthreads();
        sc[t] = v + add;
        __syncthreads();
    }
    int excl = sc[t] - c;
    if (t <= NBUCK) bstart[t] = excl;  // bstart[NBUCK] == NE
    if (t < NBUCK) bcursor[t] = excl;
}

// ---------------- bucket the edges: packed = (dstLow<<24)|src ----------------
__global__ __launch_bounds__(BHT) void k_bfill(const int* __restrict__ src,
                                               const int* __restrict__ dst,
                                               int* __restrict__ bcursor,
                                               unsigned* __restrict__ packed) {
    __shared__ int h[NBUCK];     // local hist, then local cursor
    __shared__ int hbase[NBUCK]; // reserved global base per bucket
    int t = threadIdx.x;
    for (int i = t; i < NBUCK; i += BHT) h[i] = 0;
    __syncthreads();
    long long base = (long long)blockIdx.x * EPB;
    int ed[EPT], es[EPT];
#pragma unroll
    for (int k = 0; k < EPT; ++k) {
        long long e = base + (long long)k * BHT + t;
        if (e < NE) {
            ed[k] = dst[e];
            es[k] = src[e];
            atomicAdd(&h[((unsigned)ed[k]) >> 8], 1);
        } else {
            ed[k] = -1;
            es[k] = 0;
        }
    }
    __syncthreads();
    for (int i = t; i < NBUCK; i += BHT) {
        int c = h[i];
        hbase[i] = c ? atomicAdd(&bcursor[i], c) : 0;
    }
    __syncthreads();
    for (int i = t; i < NBUCK; i += BHT) h[i] = 0;
    __syncthreads();
#pragma unroll
    for (int k = 0; k < EPT; ++k) {
        if (ed[k] >= 0) {
            unsigned d = (unsigned)ed[k];
            int b = d >> 8;
            int off = atomicAdd(&h[b], 1);
            packed[hbase[b] + off] = ((d & 255u) << 24) | (unsigned)es[k];
        }
    }
}

// ---------------- per-bucket exact sort -> rowstart, dinv, esrc ----------------
__global__ __launch_bounds__(256) void k_pass2(const int* __restrict__ bstart,
                                               const unsigned* __restrict__ packed,
                                               int* __restrict__ rowstart,
                                               float* __restrict__ dinv,
                                               int* __restrict__ esrc) {
    __shared__ int h[256], sc[256], cur[256];
    int b = blockIdx.x;
    int t = threadIdx.x;
    int dst0 = b << 8;
    int ebeg = bstart[b];
    int eend = bstart[b + 1];
    h[t] = 0;
    __syncthreads();
    for (int p = ebeg + t; p < eend; p += 256)
        atomicAdd(&h[packed[p] >> 24], 1);
    __syncthreads();
    int c = h[t];
    sc[t] = c;
    __syncthreads();
    for (int off = 1; off < 256; off <<= 1) {
        int v = sc[t];
        int add = (t >= off) ? sc[t - off] : 0;
        __syncthreads();
        sc[t] = v + add;
        __syncthreads();
    }
    int gpos = ebeg + sc[t] - c;
    int v = dst0 + t;
    if (v < NN) {
        rowstart[v] = gpos;
        dinv[v] = rsqrtf((float)(c + 1));
    }
    cur[t] = gpos;
    if (b == 0 && t == 0) rowstart[NN] = NE;
    __syncthreads();
    for (int p = ebeg + t; p < eend; p += 256) {
        unsigned pk = packed[p];
        int pos = atomicAdd(&cur[pk >> 24], 1);
        esrc[pos] = (int)(pk & 0xFFFFFFu);
    }
}

// ---------------- layer 1 transform: 4 lanes/node, 4 channels/lane ----------
// lane q loads x-row quarter [q*32, q*32+32); x values broadcast within the
// quad via DPP quad-perm (pure VALU); W row-chunk via broadcast ds_read_b128.
// No cross-lane reduction: channels are lane-owned.
__global__ __launch_bounds__(256) void k_mm1(const float* __restrict__ x,
                                             const float* __restrict__ W1,
                                             const float* __restrict__ dinv,
                                             unsigned* __restrict__ g1b) {
    __shared__ float Ws[DIN * DHID];  // 8 KB
    for (int i = threadIdx.x; i < DIN * DHID; i += 256) Ws[i] = W1[i];
    __syncthreads();
    int t = blockIdx.x * 256 + threadIdx.x;
    int v = t >> 2;
    int q = threadIdx.x & 3;
    if (v >= NN) return;
    float4 xq[8];
    const float4* xr = (const float4*)(x + (size_t)v * DIN + q * 32);
#pragma unroll
    for (int i = 0; i < 8; ++i) xq[i] = xr[i];
    const float* xs = (const float*)xq;
    float acc0 = 0.f, acc1 = 0.f, acc2 = 0.f, acc3 = 0.f;
    // quad-perm broadcast from quad-lane QQ: dpp_ctrl = QQ * 0x55
#define QSTEP(QQ, CTRL)                                                          \
    _Pragma("unroll")                                                            \
    for (int k = 0; k < 32; ++k) {                                               \
        float xv = __int_as_float(                                               \
            __builtin_amdgcn_mov_dpp(__float_as_int(xs[k]), CTRL, 0xF, 0xF, false)); \
        const float4 w = *(const float4*)&Ws[(QQ * 32 + k) * DHID + q * 4];      \
        acc0 += xv * w.x; acc1 += xv * w.y; acc2 += xv * w.z; acc3 += xv * w.w;  \
    }
    QSTEP(0, 0x00)
    QSTEP(1, 0x55)
    QSTEP(2, 0xAA)
    QSTEP(3, 0xFF)
#undef QSTEP
    float dv = dinv[v];
    unsigned u0 = f2bf(acc0 * dv) | (f2bf(acc1 * dv) << 16);
    unsigned u1 = f2bf(acc2 * dv) | (f2bf(acc3 * dv) << 16);
    ((uint2*)(g1b + (size_t)v * 8))[q] = make_uint2(u0, u1);
}

// ---------------- layer 1 gather: 8 lanes/node, 2 channels/lane, 4x unroll ----
__global__ __launch_bounds__(256) void k_gather1(const int* __restrict__ rowstart,
                                                 const int* __restrict__ esrc,
                                                 const float* __restrict__ dinv,
                                                 const unsigned* __restrict__ G,
                                                 float* __restrict__ out1) {
    int t = blockIdx.x * 256 + threadIdx.x;
    int v = t >> 3;
    int j = t & 7;
    if (v >= NN) return;
    int beg = rowstart[v];
    int end = rowstart[v + 1];
    unsigned a = G[(v << 3) + j];  // self loop
    float c0 = bflo(a), c1 = bfhi(a);
    int p = beg;
    int n4 = beg + ((end - beg) & ~3);
    for (; p < n4; p += 4) {
        int u0 = esrc[p], u1 = esrc[p + 1], u2 = esrc[p + 2], u3 = esrc[p + 3];
        unsigned b0 = G[(u0 << 3) + j];
        unsigned b1 = G[(u1 << 3) + j];
        unsigned b2 = G[(u2 << 3) + j];
        unsigned b3 = G[(u3 << 3) + j];
        c0 += bflo(b0) + bflo(b1) + bflo(b2) + bflo(b3);
        c1 += bfhi(b0) + bfhi(b1) + bfhi(b2) + bfhi(b3);
    }
    for (; p < end; ++p) {
        unsigned b = G[(esrc[p] << 3) + j];
        c0 += bflo(b);
        c1 += bfhi(b);
    }
    float dv = dinv[v];
    ((float2*)out1)[(v << 3) + j] = make_float2(c0 * dv, c1 * dv);
}

// ---------------- layer 2 transform ----------------
__global__ __launch_bounds__(256) void k_mm2(const float* __restrict__ out1,
                                             const float* __restrict__ b1,
                                             const float* __restrict__ W2,
                                             const float* __restrict__ dinv,
                                             float* __restrict__ g2) {
    int v = blockIdx.x * 256 + threadIdx.x;
    if (v >= NN) return;
    const float4* r = (const float4*)(out1 + (size_t)v * DHID);
    float h0 = 0.0f, h1 = 0.0f;
#pragma unroll
    for (int q = 0; q < 4; ++q) {
        float4 a = r[q];
        float tt[4] = {a.x, a.y, a.z, a.w};
#pragma unroll
        for (int i = 0; i < 4; ++i) {
            int j = q * 4 + i;
            float tv = fmaxf(tt[i] + b1[j], 0.0f);
            h0 += tv * W2[j * DOUT + 0];
            h1 += tv * W2[j * DOUT + 1];
        }
    }
    float dv = dinv[v];
    g2[v * 2 + 0] = h0 * dv;
    g2[v * 2 + 1] = h1 * dv;
}

// ---------------- layer 2 gather: 8 lanes/node = 4 edge-slots x 2 ch -------
__global__ __launch_bounds__(256) void k_gather2(const int* __restrict__ rowstart,
                                                 const int* __restrict__ esrc,
                                                 const float* __restrict__ dinv,
                                                 const float* __restrict__ g2,
                                                 const float* __restrict__ b2,
                                                 float* __restrict__ out) {
    int t = blockIdx.x * 256 + threadIdx.x;
    int v = t >> 3;
    if (v >= NN) return;
    int lane = t & 7;
    int ch = lane & 1;
    int slot = lane >> 1;
    int beg = rowstart[v];
    int end = rowstart[v + 1];
    float acc = 0.0f;
    for (int p = beg + slot; p < end; p += 4)
        acc += g2[(esrc[p] << 1) + ch];
    acc += __shfl_xor(acc, 2);
    acc += __shfl_xor(acc, 4);  // all slots summed; every lane has the total
    float o = (acc + g2[(v << 1) + ch]) * dinv[v] + b2[ch];
    float other = __shfl_xor(o, 1);
    float m = fmaxf(o, other);
    float lse = m + logf(expf(o - m) + expf(other - m));
    if (slot == 0) out[(v << 1) + ch] = o - lse;
}

extern "C" void kernel_launch(void* const* d_in, const int* in_sizes, int n_in,
                              void* d_out, int out_size, void* d_ws, size_t ws_size,
                              hipStream_t stream) {
    const float* x  = (const float*)d_in[0];
    const float* W1 = (const float*)d_in[1];
    const float* b1 = (const float*)d_in[2];
    const float* W2 = (const float*)d_in[3];
    const float* b2 = (const float*)d_in[4];
    const int* ei   = (const int*)d_in[5];
    const int* src = ei;
    const int* dst = ei + NE;

    // workspace (4B elems). packed (NE=12.8MB) is dead after k_pass2;
    // g1b (8NN uints = 3.2MB) and out1 (16NN floats = 6.4MB) alias it
    // (8NN + 16NN = 2.4M < NE = 3.2M). Stream order makes this safe.
    int* ws       = (int*)d_ws;
    int* bcount   = ws;                    // 400
    int* bstart   = ws + 400;              // 400 (uses NBUCK+1)
    int* bcursor  = ws + 800;              // 400
    int* rowstart = ws + 1200;             // NN+16
    float* dinv   = (float*)(ws + 1200 + NN + 16);    // NN
    int* esrc     = ws + 1200 + 2 * NN + 16;          // NE
    unsigned* packed = (unsigned*)(esrc + NE);        // NE
    unsigned* g1b = packed;                // 8*NN uints (aliases packed)
    float* out1   = (float*)(packed + 8 * NN);  // 16*NN floats (aliases packed)
    float* g2     = (float*)(packed + NE); // 2*NN

    float* out = (float*)d_out;

    const int NB_N = (NN + 255) / 256;  // 391

    k_zero_b<<<1, 512, 0, stream>>>(bcount);
    k_bhist<<<NBB, BHT, 0, stream>>>(dst, bcount);
    k_bscan<<<1, 512, 0, stream>>>(bcount, bstart, bcursor);
    k_bfill<<<NBB, BHT, 0, stream>>>(src, dst, bcursor, packed);
    k_pass2<<<NBUCK, 256, 0, stream>>>(bstart, packed, rowstart, dinv, esrc);
    k_mm1<<<(NN * 4 + 255) / 256, 256, 0, stream>>>(x, W1, dinv, g1b);
    k_gather1<<<(NN * 8 + 255) / 256, 256, 0, stream>>>(rowstart, esrc, dinv, g1b, out1);
    k_mm2<<<NB_N, 256, 0, stream>>>(out1, b1, W2, dinv, g2);
    k_gather2<<<(NN * 8 + 255) / 256, 256, 0, stream>>>(rowstart, esrc, dinv, g2, b2, out);
}